// Round 10
// baseline (185.845 us; speedup 1.0000x reference)
//
#include <hip/hip_runtime.h>
#include <hip/hip_bf16.h>
#include <cstddef>

#define BIGV 10000000.0f
#define WPV  1.0f
#define TEMPV 0.01f

// Sizes (fixed by the problem)
#define BATCH 8
#define T1N 256
#define T2N 1024
#define CN 128
#define DN 1279          // T1+T2-1

#define CSTRIDE 68       // LDS row stride in floats for 64-ch half (64+4, 16B-aligned)

// ---------------------------------------------------------------------------
// Kernel 1 (R10 rewrite): skewed cost sk[b][d][j] = mean_c |A[b,j,c]-B[b,clip(d-j),c]|
// R9 post-mortem: old 32x32 tile was LDS-read-bound (1.25 b128/cell-group,
// ~32 us of LDS-unit serialization). Now: 64x64 tile, 4x4 strided micro-tile
// -> 11 b128 per 16 cells (1.8x fewer); channel-split into two 64-ch passes
// so A(64x68)+B(127x68) fp32 = 52 KB fits static LDS; early-exit for blocks
// entirely past dEnd[b] (rows there are never consumed pre-latch by dp).
// ---------------------------------------------------------------------------
__global__ __launch_bounds__(256) void cost_kernel(const float* __restrict__ A,
                                                   const float* __restrict__ Bf,
                                                   const int* __restrict__ lenA,
                                                   const int* __restrict__ lenB,
                                                   float* __restrict__ sk) {
    __shared__ float As[64 * CSTRIDE];    // 17,408 B
    __shared__ float Bs[127 * CSTRIDE];   // 34,544 B  (total 51,952 B)

    const int b  = blockIdx.z;
    const int d0 = blockIdx.y * 64;
    const int j0 = blockIdx.x * 64;
    const int tid = threadIdx.x;

    const int dEnd = lenA[b] + lenB[b] - 2;
    if (d0 > dEnd) return;               // block-uniform: rows never needed pre-latch

    const float* Ab = A  + (size_t)b * T1N * CN;
    const float* Bb = Bf + (size_t)b * T2N * CN;

    const int tj = tid & 15;             // j = j0 + tj + 16*ji, ji in [0,4)
    const int td = tid >> 4;             // d = d0 + td + 16*dk, dk in [0,4)
    const int brow0 = td - tj + 63;      // local B row for dk==ji (in [48,78])
    const int rbase = d0 - j0 - 63;      // global B row of local row 0

    float acc[4][4];
    #pragma unroll
    for (int i = 0; i < 4; ++i)
        #pragma unroll
        for (int j = 0; j < 4; ++j) acc[i][j] = 0.0f;

    for (int h = 0; h < 2; ++h) {
        const int ch0 = h * 64;

        // stage A half-tile: 64 rows x 16 float4 = 1024 -> 4 per thread
        #pragma unroll
        for (int i = 0; i < 4; ++i) {
            int idx = tid + i * 256;
            int row = idx >> 4;
            int c4  = (idx & 15) << 2;
            float4 f = *(const float4*)(Ab + (size_t)(j0 + row) * CN + ch0 + c4);
            *(float4*)&As[row * CSTRIDE + c4] = f;
        }
        // stage B half-window: 127 rows x 16 float4 = 2032
        #pragma unroll
        for (int i = 0; i < 8; ++i) {
            int idx = tid + i * 256;
            if (idx < 2032) {
                int row = idx >> 4;
                int c4  = (idx & 15) << 2;
                int gr = rbase + row;
                gr = gr < 0 ? 0 : (gr > T2N - 1 ? T2N - 1 : gr);
                float4 f = *(const float4*)(Bb + (size_t)gr * CN + ch0 + c4);
                *(float4*)&Bs[row * CSTRIDE + c4] = f;
            }
        }
        __syncthreads();

        for (int c = 0; c < 64; c += 4) {
            float4 a4[4], bv[7];
            #pragma unroll
            for (int ji = 0; ji < 4; ++ji)
                a4[ji] = *(const float4*)&As[(tj + 16 * ji) * CSTRIDE + c];
            #pragma unroll
            for (int m = 0; m < 7; ++m)
                bv[m] = *(const float4*)&Bs[(brow0 + 16 * (m - 3)) * CSTRIDE + c];
            #pragma unroll
            for (int dk = 0; dk < 4; ++dk) {
                #pragma unroll
                for (int ji = 0; ji < 4; ++ji) {
                    float4 aa = a4[ji];
                    float4 bb = bv[dk - ji + 3];
                    acc[dk][ji] += fabsf(aa.x - bb.x) + fabsf(aa.y - bb.y)
                                 + fabsf(aa.z - bb.z) + fabsf(aa.w - bb.w);
                }
            }
        }
        __syncthreads();   // protect LDS before next half restages
    }

    #pragma unroll
    for (int dk = 0; dk < 4; ++dk) {
        int d = d0 + td + 16 * dk;
        if (d < DN) {
            size_t rowoff = ((size_t)b * DN + d) * T1N;
            #pragma unroll
            for (int ji = 0; ji < 4; ++ji) {
                int j = j0 + tj + 16 * ji;
                sk[rowoff + j] = acc[dk][ji] * (1.0f / 128.0f);
            }
        }
    }
}

// ---------------------------------------------------------------------------
// Kernel 2: wave-synchronous DP (frozen from R9: DPP wave_shr:1 cross-lane,
// p2(d)=p1(d-1) register reuse, depth-3 fenced global-load pipeline).
// ---------------------------------------------------------------------------
__global__ __launch_bounds__(64, 1) void dp_wave_kernel(const float* __restrict__ sk,
                                                        const int* __restrict__ lenA,
                                                        const int* __restrict__ lenB,
                                                        float* __restrict__ partials) {
    const int b = blockIdx.x;
    const int L = threadIdx.x;
    const int la = __builtin_amdgcn_readfirstlane(lenA[b]);
    const int lb = __builtin_amdgcn_readfirstlane(lenB[b]);
    const int dEnd = la + lb - 2;            // in [638, 1278]

    const float* skb = sk + (size_t)b * DN * T1N + L * 4;

    float v1_0 = BIGV, v1_1 = BIGV, v1_2 = BIGV, v1_3 = BIGV;
    float v2_0 = BIGV, v2_1 = BIGV, v2_2 = BIGV, v2_3 = BIGV;
    float res0 = 0.0f, res1 = 0.0f, res2 = 0.0f, res3 = 0.0f;

    float p1_prev = (L == 0) ? 0.0f : BIGV;  // pcp0 boundary column

    float4 a0, a1, a2, a3, a4, a5, a6, a7, a8, a9, a10, a11, a12, a13, a14, a15;
    float4 b0, b1, b2, b3, b4, b5, b6, b7, b8, b9, b10, b11, b12, b13, b14, b15;
    float4 c0, c1, c2, c3, c4, c5, c6, c7, c8, c9, c10, c11, c12, c13, c14, c15;

#define LOAD_ONE(Q, ROW) do {                                               \
        int _rr = (ROW); _rr = _rr > DN - 1 ? DN - 1 : _rr;                 \
        Q = *(const float4*)(skb + (size_t)_rr * T1N);                      \
    } while (0)

#define LOAD_BLK(P, BASE) do {                                              \
        LOAD_ONE(P##0,  (BASE) + 0);  LOAD_ONE(P##1,  (BASE) + 1);          \
        LOAD_ONE(P##2,  (BASE) + 2);  LOAD_ONE(P##3,  (BASE) + 3);          \
        LOAD_ONE(P##4,  (BASE) + 4);  LOAD_ONE(P##5,  (BASE) + 5);          \
        LOAD_ONE(P##6,  (BASE) + 6);  LOAD_ONE(P##7,  (BASE) + 7);          \
        LOAD_ONE(P##8,  (BASE) + 8);  LOAD_ONE(P##9,  (BASE) + 9);          \
        LOAD_ONE(P##10, (BASE) + 10); LOAD_ONE(P##11, (BASE) + 11);         \
        LOAD_ONE(P##12, (BASE) + 12); LOAD_ONE(P##13, (BASE) + 13);         \
        LOAD_ONE(P##14, (BASE) + 14); LOAD_ONE(P##15, (BASE) + 15);         \
    } while (0)

#define SHFL_UP1(SRC)                                                       \
    __int_as_float(__builtin_amdgcn_update_dpp(                             \
        __float_as_int(BIGV), __float_as_int(SRC),                          \
        0x138 /* wave_shr:1 */, 0xF, 0xF, false))

#define DP_STEP(Q, STEPI) do {                                              \
        float4 c = (Q);                                                     \
        float p1 = SHFL_UP1(v1_3);                                          \
        float p2 = p1_prev;                                                 \
        float n0 = c.x + fminf(p2,   fminf(v1_0, p1)   + WPV);              \
        float n1 = c.y + fminf(v2_0, fminf(v1_1, v1_0) + WPV);              \
        float n2 = c.z + fminf(v2_1, fminf(v1_2, v1_1) + WPV);              \
        float n3 = c.w + fminf(v2_2, fminf(v1_3, v1_2) + WPV);              \
        if ((STEPI) == dEnd) { res0 = n0; res1 = n1; res2 = n2; res3 = n3; }\
        p1_prev = p1;                                                       \
        v2_0 = v1_0; v2_1 = v1_1; v2_2 = v1_2; v2_3 = v1_3;                 \
        v1_0 = n0;   v1_1 = n1;   v1_2 = n2;   v1_3 = n3;                   \
    } while (0)

#define DP_BLK(P, BASE) do {                                                \
        DP_STEP(P##0,  (BASE) + 0);  DP_STEP(P##1,  (BASE) + 1);            \
        DP_STEP(P##2,  (BASE) + 2);  DP_STEP(P##3,  (BASE) + 3);            \
        DP_STEP(P##4,  (BASE) + 4);  DP_STEP(P##5,  (BASE) + 5);            \
        DP_STEP(P##6,  (BASE) + 6);  DP_STEP(P##7,  (BASE) + 7);            \
        DP_STEP(P##8,  (BASE) + 8);  DP_STEP(P##9,  (BASE) + 9);            \
        DP_STEP(P##10, (BASE) + 10); DP_STEP(P##11, (BASE) + 11);           \
        DP_STEP(P##12, (BASE) + 12); DP_STEP(P##13, (BASE) + 13);           \
        DP_STEP(P##14, (BASE) + 14); DP_STEP(P##15, (BASE) + 15);           \
    } while (0)

#define FENCE() __builtin_amdgcn_sched_barrier(0)

    LOAD_BLK(a, 0);
    LOAD_BLK(b, 16);
    LOAD_BLK(c, 32);

    const int nsb = dEnd / 48 + 1;
    for (int sb = 0; sb < nsb; ++sb) {
        const int base = sb * 48;
        FENCE();
        DP_BLK(a, base);
        FENCE();
        LOAD_BLK(a, base + 48);
        FENCE();
        DP_BLK(b, base + 16);
        FENCE();
        LOAD_BLK(b, base + 64);
        FENCE();
        DP_BLK(c, base + 32);
        FENCE();
        LOAD_BLK(c, base + 80);
        FENCE();
    }

    const int tcap = la - 1;
    if (L == (tcap >> 2)) {
        const int k = tcap & 3;
        float r = res0;
        if (k == 1) r = res1;
        else if (k == 2) r = res2;
        else if (k == 3) r = res3;
        partials[b] = r;
    }
#undef FENCE
#undef DP_BLK
#undef DP_STEP
#undef SHFL_UP1
#undef LOAD_BLK
#undef LOAD_ONE
}

// ---------------------------------------------------------------------------
// Kernel 3: sum the 8 per-batch losses into d_out[0]
// ---------------------------------------------------------------------------
__global__ void reduce_kernel(const float* __restrict__ partials,
                              float* __restrict__ out) {
    if (threadIdx.x == 0) {
        float s = 0.0f;
        for (int i = 0; i < BATCH; ++i) s += partials[i];
        out[0] = s;
    }
}

extern "C" void kernel_launch(void* const* d_in, const int* in_sizes, int n_in,
                              void* d_out, int out_size, void* d_ws, size_t ws_size,
                              hipStream_t stream) {
    const float* feaA = (const float*)d_in[0];
    const int*   lenA = (const int*)d_in[1];
    const float* feaB = (const float*)d_in[2];
    const int*   lenB = (const int*)d_in[3];

    float* sk = (float*)d_ws;                                   // 8*1279*256*4 = 10,477,568 B
    float* partials = (float*)((char*)d_ws + (size_t)BATCH * DN * T1N * sizeof(float));

    // K1: skewed cost. grid: 4 j-tiles x 20 d-tiles x 8 batches (64x64 tiles)
    cost_kernel<<<dim3(T1N / 64, (DN + 63) / 64, BATCH), 256, 0, stream>>>(feaA, feaB, lenA, lenB, sk);
    // K2: DP, one wave per batch
    dp_wave_kernel<<<BATCH, 64, 0, stream>>>(sk, lenA, lenB, partials);
    // K3: final sum
    reduce_kernel<<<1, 64, 0, stream>>>(partials, (float*)d_out);
}